// Round 1
// baseline (405.932 us; speedup 1.0000x reference)
//
#include <hip/hip_runtime.h>
#include <math.h>

// ---------------- problem constants ----------------
static constexpr int TOK    = 2048;   // BATCH*SEQ
static constexpr int DIM_   = 1024;
static constexpr int NE     = 8;
static constexpr int INTER_ = 1408;
static constexpr int SINT   = 2816;
static constexpr int NSLOT  = TOK * 2;  // 4096 routed assignments (top-2)

// ---------------- ws layout (bytes) ----------------
static constexpr size_t XB_OFF    = 0;                                // [2048][1024] bf16
static constexpr size_t HR_OFF    = XB_OFF + (size_t)TOK * DIM_ * 2;  // [4096][1408] bf16
static constexpr size_t HS_OFF    = HR_OFF + (size_t)NSLOT * INTER_ * 2; // [2048][2816] bf16
static constexpr size_t YS_OFF    = HS_OFF + (size_t)TOK * SINT * 2;  // [4096][1024] f32
static constexpr size_t TOPK_OFF  = YS_OFF + (size_t)NSLOT * DIM_ * 4; // [2048][2] int
static constexpr size_t SCALE_OFF = TOPK_OFF + (size_t)TOK * 2 * 4;   // [2048] f32
static constexpr size_t SLOT_OFF  = SCALE_OFF + (size_t)TOK * 4;      // [2048][2] int
static constexpr size_t ROWT_OFF  = SLOT_OFF + (size_t)TOK * 2 * 4;   // [4096] int
static constexpr size_t CNT_OFF   = ROWT_OFF + (size_t)NSLOT * 4 + 1024; // counts[8],base[8],pos[8]

// ---------------- types / helpers ----------------
typedef unsigned short u16;
typedef u16   u16x4  __attribute__((ext_vector_type(4)));
typedef u16   u16x8  __attribute__((ext_vector_type(8)));
typedef __bf16 bf16x8 __attribute__((ext_vector_type(8)));
typedef float f32x4  __attribute__((ext_vector_type(4)));

static __device__ __forceinline__ u16 f2bf(float f) {
  unsigned int u = __builtin_bit_cast(unsigned int, f);
  return (u16)((u + 0x7fffu + ((u >> 16) & 1u)) >> 16);   // RNE
}

static __device__ __forceinline__ f32x4 mfma16(u16x8 a, u16x8 b, f32x4 c) {
  return __builtin_amdgcn_mfma_f32_16x16x32_bf16(
      __builtin_bit_cast(bf16x8, a), __builtin_bit_cast(bf16x8, b), c, 0, 0, 0);
}

static __device__ __forceinline__ void gload16(const void* g, void* l) {
  __builtin_amdgcn_global_load_lds(
      (const __attribute__((address_space(1))) unsigned int*)g,
      (__attribute__((address_space(3))) unsigned int*)l, 16, 0, 0);
}

// =====================================================================
// Kernel 1: x -> bf16 conversion + gate (f64 scores, softmax, top-2)
// grid 512 x 256; one wave per token (4 tokens/block)
// =====================================================================
__global__ __launch_bounds__(256) void gate_kernel(
    const float* __restrict__ x, const float* __restrict__ gw,
    const float* __restrict__ gb, u16* __restrict__ xb,
    float* __restrict__ probs_out, float* __restrict__ idx_out,
    int* __restrict__ topk, float* __restrict__ scalep, int* __restrict__ counts)
{
  const int tid = threadIdx.x;
  // ---- convert 16 f32 -> bf16 per thread (block covers its own 4 tokens) ----
  {
    const size_t base = (size_t)blockIdx.x * 4096 + (size_t)tid * 16;
    const float4* src = (const float4*)(x + base);
    u16* dst = xb + base;
    #pragma unroll
    for (int j = 0; j < 4; ++j) {
      float4 v = src[j];
      u16x4 o = { f2bf(v.x), f2bf(v.y), f2bf(v.z), f2bf(v.w) };
      *(u16x4*)(dst + j * 4) = o;
    }
  }
  // ---- gate: one wave per token ----
  const int wid = tid >> 6, lane = tid & 63;
  const int t = blockIdx.x * 4 + wid;
  const float* xr = x + (size_t)t * DIM_;
  double part[NE] = {0,0,0,0,0,0,0,0};
  for (int it = 0; it < DIM_ / 64; ++it) {
    const int d = lane + it * 64;
    const double xv = (double)xr[d];
    #pragma unroll
    for (int e = 0; e < NE; ++e) part[e] += xv * (double)gw[e * DIM_ + d];
  }
  #pragma unroll
  for (int e = 0; e < NE; ++e) {
    #pragma unroll
    for (int off = 32; off; off >>= 1) part[e] += __shfl_xor(part[e], off);
    part[e] += (double)gb[e];
  }
  if (lane == 0) {
    double m = part[0];
    #pragma unroll
    for (int e = 1; e < NE; ++e) m = fmax(m, part[e]);
    double p[NE], sd = 0.0;
    #pragma unroll
    for (int e = 0; e < NE; ++e) { p[e] = exp(part[e] - m); sd += p[e]; }
    float pf[NE]; float sumf = 0.0f;
    #pragma unroll
    for (int e = 0; e < NE; ++e) { pf[e] = (float)(p[e] / sd); sumf += pf[e]; }
    // top-2 by f64 score (matches np f64 ref; ties -> lowest index via strict >)
    int a0 = 0;
    #pragma unroll
    for (int e = 1; e < NE; ++e) if (part[e] > part[a0]) a0 = e;
    int a1 = (a0 == 0) ? 1 : 0;
    #pragma unroll
    for (int e = 0; e < NE; ++e) if (e != a0 && part[e] > part[a1]) a1 = e;
    #pragma unroll
    for (int e = 0; e < NE; ++e) probs_out[t * NE + e] = pf[e];
    idx_out[t * 2 + 0] = (float)a0;       // whole out buffer is read back as f32
    idx_out[t * 2 + 1] = (float)a1;
    topk[t * 2 + 0] = a0; topk[t * 2 + 1] = a1;
    scalep[t] = sumf;                      // == probs.sum() (≈1), faithful to ref
    atomicAdd(&counts[a0], 1);
    atomicAdd(&counts[a1], 1);
  }
}

// counts[0..7] -> base[8..15] (exclusive prefix), zero pos[16..23]
__global__ void offsets_kernel(int* __restrict__ c) {
  if (threadIdx.x == 0) {
    int acc = 0;
    for (int e = 0; e < NE; ++e) { c[8 + e] = acc; acc += c[e]; c[16 + e] = 0; }
  }
}

__global__ __launch_bounds__(256) void scatter_kernel(
    const int* __restrict__ topk, int* __restrict__ c,
    int* __restrict__ row_token, int* __restrict__ slot_of)
{
  const int t = blockIdx.x * 256 + threadIdx.x;
  #pragma unroll
  for (int k = 0; k < 2; ++k) {
    const int e = topk[t * 2 + k];
    const int p = atomicAdd(&c[16 + e], 1);
    const int s = c[8 + e] + p;
    row_token[s] = t;
    slot_of[t * 2 + k] = s;
  }
}

// =====================================================================
// Fused dual GEMM: H = silu(A @ W1^T + b1) * (A @ W3^T + b3)  -> bf16
// A: bf16 [*,1024]; W: f32 nn.Linear layout [N][K] (per expert if GATHER)
// 128x128 tile, BK=32, 4 waves, mfma 16x16x32 bf16 (m97 structure)
// =====================================================================
template<int GATHER>
__global__ __launch_bounds__(256, 1) void gemm13_kernel(
    const u16* __restrict__ A, const int* __restrict__ row_token,
    const int* __restrict__ cb,
    const float* __restrict__ W1, const float* __restrict__ B1,
    const float* __restrict__ W3, const float* __restrict__ B3,
    int N, u16* __restrict__ Hout)
{
  constexpr int K = DIM_;              // 1024
  const int e  = blockIdx.z;
  const int mt = blockIdx.y;
  int cnt, srow0;
  if (GATHER) { cnt = cb[e]; srow0 = cb[8 + e]; }
  else        { cnt = TOK;   srow0 = 0; }
  if (mt * 128 >= cnt) return;
  const int rows_lim = cnt - mt * 128;
  const int col0 = blockIdx.x * 128;

  const float* W1e = W1 + (size_t)e * N * K;
  const float* W3e = W3 + (size_t)e * N * K;
  const float* B1e = B1 + (size_t)e * N;
  const float* B3e = B3 + (size_t)e * N;

  __shared__ alignas(16) u16 Al [128 * 32];
  __shared__ alignas(16) u16 Bl1[128 * 32];
  __shared__ alignas(16) u16 Bl3[128 * 32];

  const int tid = threadIdx.x;
  const int wid = tid >> 6, lane = tid & 63;

  // A staging: global_load_lds, LDS dest wave-uniform; global src per-lane (gather ok)
  const int ar0 = wid * 16 + (lane >> 2);
  const int ar1 = ar0 + 64;
  const int ac8 = (lane & 3) * 8;
  const u16 *srcA0, *srcA1;
  if (GATHER) {
    const int t0 = (ar0 < rows_lim) ? row_token[srow0 + mt * 128 + ar0] : 0;
    const int t1 = (ar1 < rows_lim) ? row_token[srow0 + mt * 128 + ar1] : 0;
    srcA0 = A + (size_t)t0 * K + ac8;
    srcA1 = A + (size_t)t1 * K + ac8;
  } else {
    srcA0 = A + (size_t)(mt * 128 + ar0) * K + ac8;
    srcA1 = A + (size_t)(mt * 128 + ar1) * K + ac8;
  }

  const int wr = wid >> 1, wc = wid & 1;
  const int fr = lane & 15, gr = lane >> 4;
  const int brn = tid >> 3;            // B stage row within pass (0..31)
  const int bkc = (tid & 7) * 4;       // B stage k-offset (0..28)

  f32x4 acc1[4][4] = {};
  f32x4 acc3[4][4] = {};

  for (int kt = 0; kt < K / 32; ++kt) {
    const int k0 = kt * 32;
    gload16(srcA0 + k0, Al + wid * 512);
    gload16(srcA1 + k0, Al + wid * 512 + 2048);
    #pragma unroll
    for (int ps = 0; ps < 4; ++ps) {
      const int rn = ps * 32 + brn;
      float4 v1 = *(const float4*)(W1e + (size_t)(col0 + rn) * K + k0 + bkc);
      float4 v3 = *(const float4*)(W3e + (size_t)(col0 + rn) * K + k0 + bkc);
      u16x4 o1 = { f2bf(v1.x), f2bf(v1.y), f2bf(v1.z), f2bf(v1.w) };
      u16x4 o3 = { f2bf(v3.x), f2bf(v3.y), f2bf(v3.z), f2bf(v3.w) };
      *(u16x4*)(Bl1 + rn * 32 + bkc) = o1;
      *(u16x4*)(Bl3 + rn * 32 + bkc) = o3;
    }
    __syncthreads();
    u16x8 af[4], b1f[4], b3f[4];
    #pragma unroll
    for (int i = 0; i < 4; ++i) {
      af [i] = *(const u16x8*)(Al  + (wr * 64 + i * 16 + fr) * 32 + gr * 8);
      b1f[i] = *(const u16x8*)(Bl1 + (wc * 64 + i * 16 + fr) * 32 + gr * 8);
      b3f[i] = *(const u16x8*)(Bl3 + (wc * 64 + i * 16 + fr) * 32 + gr * 8);
    }
    #pragma unroll
    for (int mi = 0; mi < 4; ++mi)
      #pragma unroll
      for (int ni = 0; ni < 4; ++ni) {
        acc1[mi][ni] = mfma16(af[mi], b1f[ni], acc1[mi][ni]);
        acc3[mi][ni] = mfma16(af[mi], b3f[ni], acc3[mi][ni]);
      }
    __syncthreads();
  }

  #pragma unroll
  for (int ni = 0; ni < 4; ++ni) {
    const int n = col0 + wc * 64 + ni * 16 + fr;
    const float bb1 = B1e[n], bb3 = B3e[n];
    #pragma unroll
    for (int mi = 0; mi < 4; ++mi) {
      const int rb = wr * 64 + mi * 16 + gr * 4;
      f32x4 v1 = acc1[mi][ni], v3 = acc3[mi][ni];
      #pragma unroll
      for (int j = 0; j < 4; ++j) {
        const int r = rb + j;
        if (r < rows_lim) {
          const float h1 = v1[j] + bb1;
          const float h3 = v3[j] + bb3;
          const float hv = (h1 / (1.0f + __expf(-h1))) * h3;   // silu(h1)*h3
          Hout[(size_t)(srow0 + mt * 128 + r) * N + n] = f2bf(hv);
        }
      }
    }
  }
}

// =====================================================================
// GEMM2: C = A @ W2^T + b2.  MODE0: -> Yslot f32 (routed, per expert)
// MODE1: shared z + fused combine: out = (Ys[s0]+Ys[s1])*scale + z
// =====================================================================
template<int MODE>
__global__ __launch_bounds__(256, 1) void gemm2_kernel(
    const u16* __restrict__ A, const int* __restrict__ cb,
    const float* __restrict__ W2, const float* __restrict__ B2,
    float* __restrict__ Ys,
    const int* __restrict__ slot_of, const float* __restrict__ scalep,
    float* __restrict__ outy)
{
  constexpr int K = (MODE == 0) ? INTER_ : SINT;   // 1408 / 2816
  const int e  = blockIdx.z;
  const int mt = blockIdx.y;
  int cnt, srow0;
  if (MODE == 0) { cnt = cb[e]; srow0 = cb[8 + e]; }
  else           { cnt = TOK;   srow0 = 0; }
  if (mt * 128 >= cnt) return;
  const int rows_lim = cnt - mt * 128;
  const int col0 = blockIdx.x * 128;
  const float* W2e = W2 + (MODE == 0 ? (size_t)e * DIM_ * K : (size_t)0);
  const float* B2e = B2 + (MODE == 0 ? (size_t)e * DIM_     : (size_t)0);

  __shared__ alignas(16) u16 Al[128 * 32];
  __shared__ alignas(16) u16 Bl[128 * 32];

  const int tid = threadIdx.x, wid = tid >> 6, lane = tid & 63;
  const int ar0 = wid * 16 + (lane >> 2), ar1 = ar0 + 64;
  const int ac8 = (lane & 3) * 8;
  const int cr0 = min(ar0, rows_lim - 1), cr1 = min(ar1, rows_lim - 1);
  const u16* srcA0 = A + (size_t)(srow0 + mt * 128 + cr0) * K + ac8;
  const u16* srcA1 = A + (size_t)(srow0 + mt * 128 + cr1) * K + ac8;

  const int wr = wid >> 1, wc = wid & 1, fr = lane & 15, gr = lane >> 4;
  const int brn = tid >> 3, bkc = (tid & 7) * 4;
  f32x4 acc[4][4] = {};

  for (int kt = 0; kt < K / 32; ++kt) {
    const int k0 = kt * 32;
    gload16(srcA0 + k0, Al + wid * 512);
    gload16(srcA1 + k0, Al + wid * 512 + 2048);
    #pragma unroll
    for (int ps = 0; ps < 4; ++ps) {
      const int rn = ps * 32 + brn;
      float4 v = *(const float4*)(W2e + (size_t)(col0 + rn) * K + k0 + bkc);
      u16x4 o = { f2bf(v.x), f2bf(v.y), f2bf(v.z), f2bf(v.w) };
      *(u16x4*)(Bl + rn * 32 + bkc) = o;
    }
    __syncthreads();
    u16x8 af[4], bf_[4];
    #pragma unroll
    for (int i = 0; i < 4; ++i) {
      af [i] = *(const u16x8*)(Al + (wr * 64 + i * 16 + fr) * 32 + gr * 8);
      bf_[i] = *(const u16x8*)(Bl + (wc * 64 + i * 16 + fr) * 32 + gr * 8);
    }
    #pragma unroll
    for (int mi = 0; mi < 4; ++mi)
      #pragma unroll
      for (int ni = 0; ni < 4; ++ni)
        acc[mi][ni] = mfma16(af[mi], bf_[ni], acc[mi][ni]);
    __syncthreads();
  }

  #pragma unroll
  for (int ni = 0; ni < 4; ++ni) {
    const int n = col0 + wc * 64 + ni * 16 + fr;
    const float bb = B2e[n];
    #pragma unroll
    for (int mi = 0; mi < 4; ++mi) {
      const int rb = wr * 64 + mi * 16 + gr * 4;
      f32x4 v = acc[mi][ni];
      #pragma unroll
      for (int j = 0; j < 4; ++j) {
        const int r = rb + j;
        if (r < rows_lim) {
          const float val = v[j] + bb;
          if (MODE == 0) {
            Ys[(size_t)(srow0 + mt * 128 + r) * DIM_ + n] = val;
          } else {
            const int t = mt * 128 + r;
            const int s0 = slot_of[t * 2], s1 = slot_of[t * 2 + 1];
            const float yv = (Ys[(size_t)s0 * DIM_ + n] + Ys[(size_t)s1 * DIM_ + n])
                             * scalep[t] + val;
            outy[(size_t)t * DIM_ + n] = yv;
          }
        }
      }
    }
  }
}

// =====================================================================
extern "C" void kernel_launch(void* const* d_in, const int* in_sizes, int n_in,
                              void* d_out, int out_size, void* d_ws, size_t ws_size,
                              hipStream_t stream) {
  (void)in_sizes; (void)n_in; (void)out_size; (void)ws_size;
  const float* x   = (const float*)d_in[0];
  const float* gw  = (const float*)d_in[1];
  const float* gb  = (const float*)d_in[2];
  const float* w1  = (const float*)d_in[3];
  const float* b1  = (const float*)d_in[4];
  const float* w2  = (const float*)d_in[5];
  const float* b2  = (const float*)d_in[6];
  const float* w3  = (const float*)d_in[7];
  const float* b3  = (const float*)d_in[8];
  const float* sw1 = (const float*)d_in[9];
  const float* sb1 = (const float*)d_in[10];
  const float* sw2 = (const float*)d_in[11];
  const float* sb2 = (const float*)d_in[12];
  const float* sw3 = (const float*)d_in[13];
  const float* sb3 = (const float*)d_in[14];

  float* out       = (float*)d_out;
  float* probs_out = out;                 // [2048][8]
  float* idx_out   = out + TOK * NE;      // [2048][2] (as float)
  float* y_out     = out + TOK * NE + TOK * 2;  // [2048][1024]

  char* ws = (char*)d_ws;
  u16*   xb        = (u16*)  (ws + XB_OFF);
  u16*   Hr        = (u16*)  (ws + HR_OFF);
  u16*   Hs        = (u16*)  (ws + HS_OFF);
  float* Ysl       = (float*)(ws + YS_OFF);
  int*   topk      = (int*)  (ws + TOPK_OFF);
  float* scalep    = (float*)(ws + SCALE_OFF);
  int*   slot_of   = (int*)  (ws + SLOT_OFF);
  int*   row_token = (int*)  (ws + ROWT_OFF);
  int*   cnts      = (int*)  (ws + CNT_OFF);

  hipMemsetAsync(cnts, 0, 128, stream);
  gate_kernel<<<TOK / 4, 256, 0, stream>>>(x, gw, gb, xb, probs_out, idx_out,
                                           topk, scalep, cnts);
  offsets_kernel<<<1, 64, 0, stream>>>(cnts);
  scatter_kernel<<<TOK / 256, 256, 0, stream>>>(topk, cnts, row_token, slot_of);
  gemm13_kernel<1><<<dim3(INTER_ / 128, 16, NE), 256, 0, stream>>>(
      xb, row_token, cnts, w1, b1, w3, b3, INTER_, Hr);
  gemm13_kernel<0><<<dim3(SINT / 128, 16, 1), 256, 0, stream>>>(
      xb, nullptr, nullptr, sw1, sb1, sw3, sb3, SINT, Hs);
  gemm2_kernel<0><<<dim3(DIM_ / 128, 16, NE), 256, 0, stream>>>(
      Hr, cnts, w2, b2, Ysl, nullptr, nullptr, nullptr);
  gemm2_kernel<1><<<dim3(DIM_ / 128, 16, 1), 256, 0, stream>>>(
      Hs, nullptr, sw2, sb2, Ysl, slot_of, scalep, y_out);
}

// Round 2
// 293.755 us; speedup vs baseline: 1.3819x; 1.3819x over previous
//
#include <hip/hip_runtime.h>
#include <math.h>

// ---------------- problem constants ----------------
static constexpr int TOK    = 2048;
static constexpr int DIM_   = 1024;
static constexpr int NE     = 8;
static constexpr int INTER_ = 1408;
static constexpr int SINT   = 2816;
static constexpr int NSLOT  = TOK * 2;

// ---------------- ws layout (bytes) ----------------
static constexpr size_t XB_OFF    = 0;                                   // [2048][1024] bf16
static constexpr size_t HR_OFF    = XB_OFF + (size_t)TOK * DIM_ * 2;     // [4096][1408] bf16
static constexpr size_t HS_OFF    = HR_OFF + (size_t)NSLOT * INTER_ * 2; // [2048][2816] bf16
static constexpr size_t YS_OFF    = HS_OFF + (size_t)TOK * SINT * 2;     // [4096][1024] f32
static constexpr size_t ZP_OFF    = YS_OFF + (size_t)NSLOT * DIM_ * 4;   // [2][2048][1024] f32
static constexpr size_t TOPK_OFF  = ZP_OFF + (size_t)2 * TOK * DIM_ * 4; // [2048][2] int
static constexpr size_t SCALE_OFF = TOPK_OFF + (size_t)TOK * 2 * 4;      // [2048] f32
static constexpr size_t SLOT_OFF  = SCALE_OFF + (size_t)TOK * 4;         // [2048][2] int
static constexpr size_t ROWT_OFF  = SLOT_OFF + (size_t)TOK * 2 * 4;      // [4096] int
static constexpr size_t CNT_OFF   = ROWT_OFF + (size_t)NSLOT * 4 + 1024;

// ---------------- types / helpers ----------------
typedef unsigned short u16;
typedef u16   u16x4  __attribute__((ext_vector_type(4)));
typedef u16   u16x8  __attribute__((ext_vector_type(8)));
typedef __bf16 bf16x8 __attribute__((ext_vector_type(8)));
typedef float f32x4  __attribute__((ext_vector_type(4)));

static __device__ __forceinline__ u16 f2bf(float f) {
  unsigned int u = __builtin_bit_cast(unsigned int, f);
  return (u16)((u + 0x7fffu + ((u >> 16) & 1u)) >> 16);   // RNE
}

static __device__ __forceinline__ f32x4 mfma16(u16x8 a, u16x8 b, f32x4 c) {
  return __builtin_amdgcn_mfma_f32_16x16x32_bf16(
      __builtin_bit_cast(bf16x8, a), __builtin_bit_cast(bf16x8, b), c, 0, 0, 0);
}

static __device__ __forceinline__ void gload16(const void* g, void* l) {
  __builtin_amdgcn_global_load_lds(
      (const __attribute__((address_space(1))) unsigned int*)g,
      (__attribute__((address_space(3))) unsigned int*)l, 16, 0, 0);
}

// =====================================================================
// Kernel 1: x -> bf16 conversion + gate (f64 scores, softmax, top-2)
// =====================================================================
__global__ __launch_bounds__(256) void gate_kernel(
    const float* __restrict__ x, const float* __restrict__ gw,
    const float* __restrict__ gb, u16* __restrict__ xb,
    float* __restrict__ probs_out, float* __restrict__ idx_out,
    int* __restrict__ topk, float* __restrict__ scalep, int* __restrict__ counts)
{
  const int tid = threadIdx.x;
  {
    const size_t base = (size_t)blockIdx.x * 4096 + (size_t)tid * 16;
    const float4* src = (const float4*)(x + base);
    u16* dst = xb + base;
    #pragma unroll
    for (int j = 0; j < 4; ++j) {
      float4 v = src[j];
      u16x4 o = { f2bf(v.x), f2bf(v.y), f2bf(v.z), f2bf(v.w) };
      *(u16x4*)(dst + j * 4) = o;
    }
  }
  const int wid = tid >> 6, lane = tid & 63;
  const int t = blockIdx.x * 4 + wid;
  const float* xr = x + (size_t)t * DIM_;
  double part[NE] = {0,0,0,0,0,0,0,0};
  for (int it = 0; it < DIM_ / 64; ++it) {
    const int d = lane + it * 64;
    const double xv = (double)xr[d];
    #pragma unroll
    for (int e = 0; e < NE; ++e) part[e] += xv * (double)gw[e * DIM_ + d];
  }
  #pragma unroll
  for (int e = 0; e < NE; ++e) {
    #pragma unroll
    for (int off = 32; off; off >>= 1) part[e] += __shfl_xor(part[e], off);
    part[e] += (double)gb[e];
  }
  if (lane == 0) {
    double m = part[0];
    #pragma unroll
    for (int e = 1; e < NE; ++e) m = fmax(m, part[e]);
    double p[NE], sd = 0.0;
    #pragma unroll
    for (int e = 0; e < NE; ++e) { p[e] = exp(part[e] - m); sd += p[e]; }
    float pf[NE]; float sumf = 0.0f;
    #pragma unroll
    for (int e = 0; e < NE; ++e) { pf[e] = (float)(p[e] / sd); sumf += pf[e]; }
    int a0 = 0;
    #pragma unroll
    for (int e = 1; e < NE; ++e) if (part[e] > part[a0]) a0 = e;
    int a1 = (a0 == 0) ? 1 : 0;
    #pragma unroll
    for (int e = 0; e < NE; ++e) if (e != a0 && part[e] > part[a1]) a1 = e;
    #pragma unroll
    for (int e = 0; e < NE; ++e) probs_out[t * NE + e] = pf[e];
    idx_out[t * 2 + 0] = (float)a0;
    idx_out[t * 2 + 1] = (float)a1;
    topk[t * 2 + 0] = a0; topk[t * 2 + 1] = a1;
    scalep[t] = sumf;
    atomicAdd(&counts[a0], 1);
    atomicAdd(&counts[a1], 1);
  }
}

__global__ void offsets_kernel(int* __restrict__ c) {
  if (threadIdx.x == 0) {
    int acc = 0;
    for (int e = 0; e < NE; ++e) { c[8 + e] = acc; acc += c[e]; c[16 + e] = 0; }
  }
}

__global__ __launch_bounds__(256) void scatter_kernel(
    const int* __restrict__ topk, int* __restrict__ c,
    int* __restrict__ row_token, int* __restrict__ slot_of)
{
  const int t = blockIdx.x * 256 + threadIdx.x;
  #pragma unroll
  for (int k = 0; k < 2; ++k) {
    const int e = topk[t * 2 + k];
    const int p = atomicAdd(&c[16 + e], 1);
    const int s = c[8 + e] + p;
    row_token[s] = t;
    slot_of[t * 2 + k] = s;
  }
}

// =====================================================================
// g13 mega: z<8 routed experts (gathered A); z=8,9 shared N-halves.
// BM=128, BN=64, K=1024. Double-buffered LDS, 1 barrier/K-step, prefetch.
// H = silu(A@W1^T + b1) * (A@W3^T + b3) -> bf16
// =====================================================================
__global__ __launch_bounds__(256, 1) void g13_kernel(
    const u16* __restrict__ xb, const int* __restrict__ row_token,
    const int* __restrict__ cb,
    const float* __restrict__ w1, const float* __restrict__ b1,
    const float* __restrict__ w3, const float* __restrict__ b3,
    const float* __restrict__ sw1, const float* __restrict__ sb1,
    const float* __restrict__ sw3, const float* __restrict__ sb3,
    u16* __restrict__ Hr, u16* __restrict__ Hs)
{
  constexpr int K = DIM_;          // 1024
  constexpr int NT = K / 32;       // 32
  const int z = blockIdx.z, mt = blockIdx.y, col0 = blockIdx.x * 64;
  const int tid = threadIdx.x, wid = tid >> 6, lane = tid & 63;
  const int sr0 = wid * 16 + (lane >> 2), sr1 = sr0 + 64, sc = (lane & 3) * 8;

  const float *W1, *W3, *B1, *B3;
  const u16 *pa0, *pa1;
  u16* Hbase; int ldh, rows_lim;

  if (z < NE) {
    const int cnt = cb[z];
    if (mt * 128 >= cnt) return;
    rows_lim = cnt - mt * 128;
    W1 = w1 + (size_t)z * INTER_ * K;  W3 = w3 + (size_t)z * INTER_ * K;
    B1 = b1 + z * INTER_;              B3 = b3 + z * INTER_;
    const int sbase = cb[8 + z] + mt * 128;
    const int t0 = (sr0 < rows_lim) ? row_token[sbase + sr0] : 0;
    const int t1 = (sr1 < rows_lim) ? row_token[sbase + sr1] : 0;
    pa0 = xb + (size_t)t0 * K + sc;
    pa1 = xb + (size_t)t1 * K + sc;
    Hbase = Hr + (size_t)sbase * INTER_;  ldh = INTER_;
  } else {
    const int h = z - NE;
    rows_lim = 128;
    W1 = sw1 + (size_t)h * INTER_ * K;  W3 = sw3 + (size_t)h * INTER_ * K;
    B1 = sb1 + h * INTER_;              B3 = sb3 + h * INTER_;
    pa0 = xb + (size_t)(mt * 128 + sr0) * K + sc;
    pa1 = xb + (size_t)(mt * 128 + sr1) * K + sc;
    Hbase = Hs + (size_t)(mt * 128) * SINT + h * INTER_;  ldh = SINT;
  }

  __shared__ alignas(16) u16 Al [2][128 * 32];
  __shared__ alignas(16) u16 Bl1[2][64 * 32];
  __shared__ alignas(16) u16 Bl3[2][64 * 32];

  // B staging mapping: 2 rows x 1 float4 per matrix per thread
  const int br0 = tid >> 3, br1 = br0 + 32, bc = (tid & 7) * 4;
  const float* q1r0 = W1 + (size_t)(col0 + br0) * K + bc;
  const float* q1r1 = W1 + (size_t)(col0 + br1) * K + bc;
  const float* q3r0 = W3 + (size_t)(col0 + br0) * K + bc;
  const float* q3r1 = W3 + (size_t)(col0 + br1) * K + bc;

  float4 a1A = *(const float4*)(q1r0), a1B = *(const float4*)(q1r1);
  float4 a3A = *(const float4*)(q3r0), a3B = *(const float4*)(q3r1);

  gload16(pa0, &Al[0][wid * 512]);
  gload16(pa1, &Al[0][wid * 512 + 2048]);

  {
    u16x4 o;
    o = (u16x4){f2bf(a1A.x),f2bf(a1A.y),f2bf(a1A.z),f2bf(a1A.w)};
    *(u16x4*)(&Bl1[0][br0 * 32 + bc]) = o;
    o = (u16x4){f2bf(a1B.x),f2bf(a1B.y),f2bf(a1B.z),f2bf(a1B.w)};
    *(u16x4*)(&Bl1[0][br1 * 32 + bc]) = o;
    o = (u16x4){f2bf(a3A.x),f2bf(a3A.y),f2bf(a3A.z),f2bf(a3A.w)};
    *(u16x4*)(&Bl3[0][br0 * 32 + bc]) = o;
    o = (u16x4){f2bf(a3B.x),f2bf(a3B.y),f2bf(a3B.z),f2bf(a3B.w)};
    *(u16x4*)(&Bl3[0][br1 * 32 + bc]) = o;
  }
  a1A = *(const float4*)(q1r0 + 32); a1B = *(const float4*)(q1r1 + 32);
  a3A = *(const float4*)(q3r0 + 32); a3B = *(const float4*)(q3r1 + 32);
  __syncthreads();

  const int wr = wid >> 1, wc = wid & 1, fr = lane & 15, gr = lane >> 4;
  f32x4 acc1[4][2] = {}, acc3[4][2] = {};
  int p = 0;

  #pragma unroll 1
  for (int kt = 0; kt < NT; ++kt) {
    const bool hn = (kt + 1 < NT), hn2 = (kt + 2 < NT);
    if (hn) {
      const int ko = (kt + 1) * 32;
      gload16(pa0 + ko, &Al[p ^ 1][wid * 512]);
      gload16(pa1 + ko, &Al[p ^ 1][wid * 512 + 2048]);
      u16x4 o;
      o = (u16x4){f2bf(a1A.x),f2bf(a1A.y),f2bf(a1A.z),f2bf(a1A.w)};
      *(u16x4*)(&Bl1[p ^ 1][br0 * 32 + bc]) = o;
      o = (u16x4){f2bf(a1B.x),f2bf(a1B.y),f2bf(a1B.z),f2bf(a1B.w)};
      *(u16x4*)(&Bl1[p ^ 1][br1 * 32 + bc]) = o;
      o = (u16x4){f2bf(a3A.x),f2bf(a3A.y),f2bf(a3A.z),f2bf(a3A.w)};
      *(u16x4*)(&Bl3[p ^ 1][br0 * 32 + bc]) = o;
      o = (u16x4){f2bf(a3B.x),f2bf(a3B.y),f2bf(a3B.z),f2bf(a3B.w)};
      *(u16x4*)(&Bl3[p ^ 1][br1 * 32 + bc]) = o;
    }
    if (hn2) {
      const int ko = (kt + 2) * 32;
      a1A = *(const float4*)(q1r0 + ko); a1B = *(const float4*)(q1r1 + ko);
      a3A = *(const float4*)(q3r0 + ko); a3B = *(const float4*)(q3r1 + ko);
    }
    u16x8 af[4], b1f[2], b3f[2];
    #pragma unroll
    for (int i = 0; i < 4; ++i)
      af[i] = *(const u16x8*)(&Al[p][(wr * 64 + i * 16 + fr) * 32 + gr * 8]);
    #pragma unroll
    for (int i = 0; i < 2; ++i) {
      b1f[i] = *(const u16x8*)(&Bl1[p][(wc * 32 + i * 16 + fr) * 32 + gr * 8]);
      b3f[i] = *(const u16x8*)(&Bl3[p][(wc * 32 + i * 16 + fr) * 32 + gr * 8]);
    }
    #pragma unroll
    for (int mi = 0; mi < 4; ++mi)
      #pragma unroll
      for (int ni = 0; ni < 2; ++ni) {
        acc1[mi][ni] = mfma16(af[mi], b1f[ni], acc1[mi][ni]);
        acc3[mi][ni] = mfma16(af[mi], b3f[ni], acc3[mi][ni]);
      }
    if (hn) { __syncthreads(); p ^= 1; }
  }

  #pragma unroll
  for (int ni = 0; ni < 2; ++ni) {
    const int gcol = col0 + wc * 32 + ni * 16 + fr;
    const float bb1 = B1[gcol], bb3 = B3[gcol];
    #pragma unroll
    for (int mi = 0; mi < 4; ++mi) {
      const int rb = wr * 64 + mi * 16 + gr * 4;
      #pragma unroll
      for (int j = 0; j < 4; ++j) {
        const int r = rb + j;
        if (r < rows_lim) {
          const float h1 = acc1[mi][ni][j] + bb1;
          const float h3 = acc3[mi][ni][j] + bb3;
          const float hv = (h1 / (1.0f + __expf(-h1))) * h3;
          Hbase[(size_t)r * ldh + gcol] = f2bf(hv);
        }
      }
    }
  }
}

// =====================================================================
// g2 mega: z<8 routed (A=Hr slots, W=w2[e], out=Ys+b2); z=8,9 shared
// split-K halves (A=Hs cols, W=sw2 cols, out=Zp[h], no bias).
// BM=128, BN=64, K=1408. Same pipeline as g13.
// =====================================================================
__global__ __launch_bounds__(256, 1) void g2_kernel(
    const u16* __restrict__ Hr, const u16* __restrict__ Hs,
    const int* __restrict__ cb,
    const float* __restrict__ w2, const float* __restrict__ b2,
    const float* __restrict__ sw2,
    float* __restrict__ Ys, float* __restrict__ Zp)
{
  constexpr int K = INTER_;        // 1408
  constexpr int NT = K / 32;       // 44
  const int z = blockIdx.z, mt = blockIdx.y, col0 = blockIdx.x * 64;
  const int tid = threadIdx.x, wid = tid >> 6, lane = tid & 63;
  const int sr0 = wid * 16 + (lane >> 2), sr1 = sr0 + 64, sc = (lane & 3) * 8;

  const u16 *pa0, *pa1;
  const float *W, *BB;
  float* Obase;
  int rows_lim, ldw;

  if (z < NE) {
    const int cnt = cb[z];
    if (mt * 128 >= cnt) return;
    rows_lim = cnt - mt * 128;
    const int sbase = cb[8 + z] + mt * 128;
    const int r0 = min(sr0, rows_lim - 1), r1 = min(sr1, rows_lim - 1);
    pa0 = Hr + (size_t)(sbase + r0) * INTER_ + sc;
    pa1 = Hr + (size_t)(sbase + r1) * INTER_ + sc;
    W = w2 + (size_t)z * DIM_ * INTER_;  ldw = INTER_;
    BB = b2 + z * DIM_;
    Obase = Ys + (size_t)sbase * DIM_;
  } else {
    const int h = z - NE;
    rows_lim = 128;
    pa0 = Hs + (size_t)(mt * 128 + sr0) * SINT + h * INTER_ + sc;
    pa1 = Hs + (size_t)(mt * 128 + sr1) * SINT + h * INTER_ + sc;
    W = sw2 + (size_t)h * INTER_;  ldw = SINT;
    BB = nullptr;
    Obase = Zp + (size_t)h * TOK * DIM_ + (size_t)(mt * 128) * DIM_;
  }

  __shared__ alignas(16) u16 Al[2][128 * 32];
  __shared__ alignas(16) u16 Bl[2][64 * 32];

  const int br0 = tid >> 3, br1 = br0 + 32, bc = (tid & 7) * 4;
  const float* qr0 = W + (size_t)(col0 + br0) * ldw + bc;
  const float* qr1 = W + (size_t)(col0 + br1) * ldw + bc;

  float4 aA = *(const float4*)(qr0), aB = *(const float4*)(qr1);

  gload16(pa0, &Al[0][wid * 512]);
  gload16(pa1, &Al[0][wid * 512 + 2048]);
  {
    u16x4 o;
    o = (u16x4){f2bf(aA.x),f2bf(aA.y),f2bf(aA.z),f2bf(aA.w)};
    *(u16x4*)(&Bl[0][br0 * 32 + bc]) = o;
    o = (u16x4){f2bf(aB.x),f2bf(aB.y),f2bf(aB.z),f2bf(aB.w)};
    *(u16x4*)(&Bl[0][br1 * 32 + bc]) = o;
  }
  aA = *(const float4*)(qr0 + 32); aB = *(const float4*)(qr1 + 32);
  __syncthreads();

  const int wr = wid >> 1, wc = wid & 1, fr = lane & 15, gr = lane >> 4;
  f32x4 acc[4][2] = {};
  int p = 0;

  #pragma unroll 1
  for (int kt = 0; kt < NT; ++kt) {
    const bool hn = (kt + 1 < NT), hn2 = (kt + 2 < NT);
    if (hn) {
      const int ko = (kt + 1) * 32;
      gload16(pa0 + ko, &Al[p ^ 1][wid * 512]);
      gload16(pa1 + ko, &Al[p ^ 1][wid * 512 + 2048]);
      u16x4 o;
      o = (u16x4){f2bf(aA.x),f2bf(aA.y),f2bf(aA.z),f2bf(aA.w)};
      *(u16x4*)(&Bl[p ^ 1][br0 * 32 + bc]) = o;
      o = (u16x4){f2bf(aB.x),f2bf(aB.y),f2bf(aB.z),f2bf(aB.w)};
      *(u16x4*)(&Bl[p ^ 1][br1 * 32 + bc]) = o;
    }
    if (hn2) {
      const int ko = (kt + 2) * 32;
      aA = *(const float4*)(qr0 + ko); aB = *(const float4*)(qr1 + ko);
    }
    u16x8 af[4], bf_[2];
    #pragma unroll
    for (int i = 0; i < 4; ++i)
      af[i] = *(const u16x8*)(&Al[p][(wr * 64 + i * 16 + fr) * 32 + gr * 8]);
    #pragma unroll
    for (int i = 0; i < 2; ++i)
      bf_[i] = *(const u16x8*)(&Bl[p][(wc * 32 + i * 16 + fr) * 32 + gr * 8]);
    #pragma unroll
    for (int mi = 0; mi < 4; ++mi)
      #pragma unroll
      for (int ni = 0; ni < 2; ++ni)
        acc[mi][ni] = mfma16(af[mi], bf_[ni], acc[mi][ni]);
    if (hn) { __syncthreads(); p ^= 1; }
  }

  #pragma unroll
  for (int ni = 0; ni < 2; ++ni) {
    const int gcol = col0 + wc * 32 + ni * 16 + fr;
    const float bb = BB ? BB[gcol] : 0.0f;
    #pragma unroll
    for (int mi = 0; mi < 4; ++mi) {
      const int rb = wr * 64 + mi * 16 + gr * 4;
      #pragma unroll
      for (int j = 0; j < 4; ++j) {
        const int r = rb + j;
        if (r < rows_lim)
          Obase[(size_t)r * DIM_ + gcol] = acc[mi][ni][j] + bb;
      }
    }
  }
}

// =====================================================================
// combine: y = (Ys[s0]+Ys[s1])*scale + Zp0 + Zp1 + sb2
// =====================================================================
__global__ __launch_bounds__(256) void combine_kernel(
    const float* __restrict__ Ys, const float* __restrict__ Zp,
    const int* __restrict__ slot_of, const float* __restrict__ scalep,
    const float* __restrict__ sb2, float* __restrict__ y_out)
{
  const int gid = blockIdx.x * 256 + threadIdx.x;
  const int t = gid >> 8, c = (gid & 255) * 4;
  const int s0 = slot_of[t * 2], s1 = slot_of[t * 2 + 1];
  const float s = scalep[t];
  float4 a  = *(const float4*)(Ys + (size_t)s0 * DIM_ + c);
  float4 b  = *(const float4*)(Ys + (size_t)s1 * DIM_ + c);
  float4 z0 = *(const float4*)(Zp + (size_t)t * DIM_ + c);
  float4 z1 = *(const float4*)(Zp + (size_t)TOK * DIM_ + (size_t)t * DIM_ + c);
  float4 sb = *(const float4*)(sb2 + c);
  float4 o;
  o.x = (a.x + b.x) * s + z0.x + z1.x + sb.x;
  o.y = (a.y + b.y) * s + z0.y + z1.y + sb.y;
  o.z = (a.z + b.z) * s + z0.z + z1.z + sb.z;
  o.w = (a.w + b.w) * s + z0.w + z1.w + sb.w;
  *(float4*)(y_out + (size_t)t * DIM_ + c) = o;
}

// =====================================================================
extern "C" void kernel_launch(void* const* d_in, const int* in_sizes, int n_in,
                              void* d_out, int out_size, void* d_ws, size_t ws_size,
                              hipStream_t stream) {
  (void)in_sizes; (void)n_in; (void)out_size; (void)ws_size;
  const float* x   = (const float*)d_in[0];
  const float* gw  = (const float*)d_in[1];
  const float* gb  = (const float*)d_in[2];
  const float* w1  = (const float*)d_in[3];
  const float* b1  = (const float*)d_in[4];
  const float* w2  = (const float*)d_in[5];
  const float* b2  = (const float*)d_in[6];
  const float* w3  = (const float*)d_in[7];
  const float* b3  = (const float*)d_in[8];
  const float* sw1 = (const float*)d_in[9];
  const float* sb1 = (const float*)d_in[10];
  const float* sw2 = (const float*)d_in[11];
  const float* sb2 = (const float*)d_in[12];
  const float* sw3 = (const float*)d_in[13];
  const float* sb3 = (const float*)d_in[14];

  float* out       = (float*)d_out;
  float* probs_out = out;
  float* idx_out   = out + TOK * NE;
  float* y_out     = out + TOK * NE + TOK * 2;

  char* ws = (char*)d_ws;
  u16*   xb        = (u16*)  (ws + XB_OFF);
  u16*   Hr        = (u16*)  (ws + HR_OFF);
  u16*   Hs        = (u16*)  (ws + HS_OFF);
  float* Ysl       = (float*)(ws + YS_OFF);
  float* Zp        = (float*)(ws + ZP_OFF);
  int*   topk      = (int*)  (ws + TOPK_OFF);
  float* scalep    = (float*)(ws + SCALE_OFF);
  int*   slot_of   = (int*)  (ws + SLOT_OFF);
  int*   row_token = (int*)  (ws + ROWT_OFF);
  int*   cnts      = (int*)  (ws + CNT_OFF);

  hipMemsetAsync(cnts, 0, 128, stream);
  gate_kernel<<<TOK / 4, 256, 0, stream>>>(x, gw, gb, xb, probs_out, idx_out,
                                           topk, scalep, cnts);
  offsets_kernel<<<1, 64, 0, stream>>>(cnts);
  scatter_kernel<<<TOK / 256, 256, 0, stream>>>(topk, cnts, row_token, slot_of);
  g13_kernel<<<dim3(INTER_ / 64, 16, NE + 2), 256, 0, stream>>>(
      xb, row_token, cnts, w1, b1, w3, b3, sw1, sb1, sw3, sb3, Hr, Hs);
  g2_kernel<<<dim3(DIM_ / 64, 16, NE + 2), 256, 0, stream>>>(
      Hr, Hs, cnts, w2, b2, sw2, Ysl, Zp);
  combine_kernel<<<TOK, 256, 0, stream>>>(Ysl, Zp, slot_of, scalep, sb2, y_out);
}